// Round 1
// 176.979 us; speedup vs baseline: 1.0619x; 1.0619x over previous
//
#include <hip/hip_runtime.h>
#include <stdint.h>

#define V3 110592        // 48*48*48
#define PLANE 2304       // 48*48
#define NO 64

typedef unsigned short ushort_t;
typedef __attribute__((ext_vector_type(8))) short short8v;
typedef __attribute__((ext_vector_type(4))) float float4v;

__device__ __forceinline__ uint32_t f2bf1(float f) {
  uint32_t u = __float_as_uint(f);
  u += 0x7FFFu + ((u >> 16) & 1u);   // RNE
  return u >> 16;
}
__device__ __forceinline__ uint32_t pack2(float a, float b) {
  return f2bf1(a) | (f2bf1(b) << 16);
}

// ---------- prep: Afr[g=kk/8][m][8] bf16, kk = dzi*192 + i*6 + qi ----------
__global__ void prep_kernel(const float* __restrict__ w, ushort_t* __restrict__ Afr) {
  int idx = blockIdx.x * 256 + threadIdx.x;     // 120*64*8 = 61440
  if (idx >= 120 * 64 * 8) return;
  int r = idx & 7, m = (idx >> 3) & 63, g = idx >> 9;
  int kk = g * 8 + r;
  int dzi = kk / 192, k2 = kk % 192;
  int i = k2 / 6, qi = k2 % 6;
  const int Q[6] = {0, 1, 2, 4, 5, 8};
  const int pidx[13] = {0, 1, 2, 3, 4, 5, 6, 0, 7, 8, 0, 0, 9};  // r2 -> shell
  int dz = dzi - 2;
  int p = pidx[Q[qi] + dz * dz];
  Afr[idx] = (ushort_t)f2bf1(0.28209479177387814f * w[(m * 32 + i) * 10 + p]);
}

// ---------- pass 1: per-plane 2D class sums; NO LDS, NO barriers ----------
// wave-autonomous: lanes = w (52 active incl. halo), shfl for dx, rolling regs
// for dy. Bq layout [G = d*24 + g][n][8] bf16, G-groups of 8 k' (k' = i*6+qi).
__global__ __launch_bounds__(256) void bq_kernel(const float* __restrict__ x,
                                                 ushort_t* __restrict__ Bq) {
  const int tid = threadIdx.x;
  const int lane = tid & 63;
  const int strip = tid >> 6;                    // 0..3, 12 h-rows each
  const int d = blockIdx.x;                      // 0..47
  const int ig = blockIdx.y;                     // 0..7
  const float* xb = x + (size_t)blockIdx.z * 32 * V3;
  ushort_t* Bqb = Bq + (size_t)blockIdx.z * ((size_t)1152 * PLANE * 8);

  const int h0 = strip * 12;
  const int gw = lane - 2;
  const bool okw = (gw >= 0 && gw < 48);
  const int sl1 = lane > 0 ? lane - 1 : 0;
  const int sl2 = lane > 1 ? lane - 2 : 0;
  const int sr1 = lane < 63 ? lane + 1 : 63;
  const int sr2 = lane < 62 ? lane + 2 : 63;
  const bool okst = (lane >= 2 && lane <= 49);

  const float* px[4];
#pragma unroll
  for (int ii = 0; ii < 4; ++ii)
    px[ii] = xb + ((size_t)(ig * 4 + ii) * 48 + d) * PLANE + gw;

  float a0[4][5], s1[4][5], s4[4][5];            // rolling 5-row windows

#pragma unroll
  for (int r = 0; r < 16; ++r) {
    const int gh = h0 - 2 + r;
    const bool okv = okw && (gh >= 0) && (gh < 48);
    const int slot = r % 5;
#pragma unroll
    for (int ii = 0; ii < 4; ++ii) {
      float v = okv ? px[ii][gh * 48] : 0.f;
      float vl1 = __shfl(v, sl1);
      float vr1 = __shfl(v, sr1);
      float vl2 = __shfl(v, sl2);
      float vr2 = __shfl(v, sr2);
      a0[ii][slot] = v;                          // dx^2 = 0
      s1[ii][slot] = vl1 + vr1;                  // dx^2 = 1
      s4[ii][slot] = vl2 + vr2;                  // dx^2 = 4
    }
    if (r >= 4) {
      const int j0 = (r - 4) % 5, j1 = (r - 3) % 5, j2 = (r - 2) % 5,
                j3 = (r - 1) % 5, j4 = r % 5;    // j = dy offset 0..4
      uint32_t dw[12];
#pragma unroll
      for (int ii = 0; ii < 4; ++ii) {
        float B0 = a0[ii][j2];
        float B1 = s1[ii][j2] + a0[ii][j1] + a0[ii][j3];
        float B2 = s1[ii][j1] + s1[ii][j3];
        float B3 = s4[ii][j2] + a0[ii][j0] + a0[ii][j4];
        float B4 = s4[ii][j1] + s4[ii][j3] + s1[ii][j0] + s1[ii][j4];
        float B5 = s4[ii][j0] + s4[ii][j4];
        dw[ii * 3 + 0] = pack2(B0, B1);
        dw[ii * 3 + 1] = pack2(B2, B3);
        dw[ii * 3 + 2] = pack2(B4, B5);
      }
      if (okst) {
        const int n = (h0 + r - 4) * 48 + gw;
        const size_t gb = (size_t)(d * 24 + ig * 3);
        uint4 c0 = {dw[0], dw[1], dw[2], dw[3]};
        uint4 c1 = {dw[4], dw[5], dw[6], dw[7]};
        uint4 c2 = {dw[8], dw[9], dw[10], dw[11]};
        *(uint4*)(Bqb + ((gb + 0) * PLANE + n) * 8) = c0;
        *(uint4*)(Bqb + ((gb + 1) * PLANE + n) * 8) = c1;
        *(uint4*)(Bqb + ((gb + 2) * PLANE + n) * 8) = c2;
      }
    }
  }
}

// ---------- pass 2: plane-major GEMM, K = 960 linear walk, ping-pong frags ----------
// out[m][d,n] = sum_kk Afr[kk][m] * Bq[(d-2)*24 + kk/8][n][kk%8] + bias[m]
// XCD-aware partitioning: flat blockIdx b in [0,864); hardware round-robins
// b%8 across the 8 XCDs. Partition p = b&7 = (d_group<<1)|n_half owns
// d in [d_group*12, d_group*12+12) x n-half. Its Bq working set is 16 source
// half-planes (~7 MB) pinned to ONE XCD's L2, so each source plane's Bq is
// fetched ~once and reused by the 5 output d's that consume it (was 5x HBM
// re-read = 207.8 MB FETCH with blocks scattered across XCDs).
__global__ __launch_bounds__(256) void gemm_kernel(const ushort_t* __restrict__ Bq,
                                                   const ushort_t* __restrict__ Afr,
                                                   const float* __restrict__ bias,
                                                   float* __restrict__ out) {
  const int tid = threadIdx.x;
  const int lane = tid & 63, wi = tid >> 6;
  const int quad = lane >> 4, m15 = lane & 15;
  const int b = blockIdx.x;                      // 0..863 flat
  const int p = b & 7;                           // XCD partition
  const int s = b >> 3;                          // 0..107 within partition
  const int dl = s / 9;                          // 0..11
  const int nbl = s - dl * 9;                    // 0..8
  const int d = (p >> 1) * 12 + dl;              // output plane
  const int n0 = ((p & 1) * 9 + nbl) * 128 + wi * 32;
  const ushort_t* Bqb = Bq + (size_t)blockIdx.z * ((size_t)1152 * PLANE * 8);
  float* outb = out + (size_t)blockIdx.z * (size_t)NO * V3;

  const int lo = (d < 2) ? (2 - d) : 0;          // dzi range [lo,hi]
  const int hi = (d > 45) ? (49 - d) : 4;
  const int kslo = 6 * lo;
  const int T = 6 * (hi - lo + 1);               // trips: 18/24/30, always even

  const ushort_t* ap = Afr + ((size_t)(kslo * 4 + quad) * 64 + m15) * 8;
  const ushort_t* bp = Bqb + ((size_t)((d - 2) * 24 + kslo * 4 + quad) * PLANE + n0 + m15) * 8;
  const int astep = 4 * 64 * 8;                  // shorts per ks
  const int bstep = 4 * PLANE * 8;

  float4v acc[4][2];
#pragma unroll
  for (int mt = 0; mt < 4; ++mt)
#pragma unroll
    for (int nt = 0; nt < 2; ++nt) acc[mt][nt] = (float4v){0.f, 0.f, 0.f, 0.f};

  short8v A0[4], B0[2], A1[4], B1[2];

#define LOADSET(Ax, Bx)                                                        \
  {                                                                            \
    _Pragma("unroll") for (int mt = 0; mt < 4; ++mt)                           \
        Ax[mt] = *(const short8v*)(ap + mt * 128);                             \
    _Pragma("unroll") for (int nt = 0; nt < 2; ++nt)                           \
        Bx[nt] = *(const short8v*)(bp + nt * 128);                             \
    ap += astep; bp += bstep;                                                  \
  }
#define MFMASET(Ax, Bx)                                                        \
  {                                                                            \
    _Pragma("unroll") for (int mt = 0; mt < 4; ++mt)                           \
        _Pragma("unroll") for (int nt = 0; nt < 2; ++nt)                       \
            acc[mt][nt] = __builtin_amdgcn_mfma_f32_16x16x32_bf16(             \
                Ax[mt], Bx[nt], acc[mt][nt], 0, 0, 0);                         \
  }

  LOADSET(A0, B0);
  for (int k = 1; k + 1 < T; k += 2) {
    LOADSET(A1, B1);
    MFMASET(A0, B0);
    LOADSET(A0, B0);
    MFMASET(A1, B1);
  }
  LOADSET(A1, B1);
  MFMASET(A0, B0);
  MFMASET(A1, B1);
#undef LOADSET
#undef MFMASET

  // C/D: col(n) = lane&15, row(m) = quad*4 + reg
  const int vb = d * PLANE + n0 + m15;
#pragma unroll
  for (int mt = 0; mt < 4; ++mt) {
#pragma unroll
    for (int r = 0; r < 4; ++r) {
      int m = mt * 16 + quad * 4 + r;
      float bv = bias[m];
      float* op = outb + (size_t)m * V3 + vb;
#pragma unroll
      for (int nt = 0; nt < 2; ++nt)
        op[nt * 16] = acc[mt][nt][r] + bv;
    }
  }
}

extern "C" void kernel_launch(void* const* d_in, const int* in_sizes, int n_in,
                              void* d_out, int out_size, void* d_ws, size_t ws_size,
                              hipStream_t stream) {
  const float* x    = (const float*)d_in[0];   // [2,32,1,48,48,48]
  const float* w    = (const float*)d_in[1];   // [64,32,1,1,1,10]
  const float* bias = (const float*)d_in[2];   // [64]
  float* out = (float*)d_out;                  // [2,64,1,48,48,48]

  ushort_t* Afr = (ushort_t*)d_ws;                         // 122880 B
  ushort_t* Bq  = (ushort_t*)((char*)d_ws + 131072);
  const size_t SB = (size_t)1152 * PLANE * 8 * 2;          // 42.5 MB per batch
  const bool both = (ws_size >= 131072 + 2 * SB);

  prep_kernel<<<240, 256, 0, stream>>>(w, Afr);
  if (both) {
    bq_kernel<<<dim3(48, 8, 2), 256, 0, stream>>>(x, Bq);
    gemm_kernel<<<dim3(864, 1, 2), 256, 0, stream>>>(Bq, Afr, bias, out);
  } else {
    for (int b = 0; b < 2; ++b) {
      bq_kernel<<<dim3(48, 8, 1), 256, 0, stream>>>(x + (size_t)b * 32 * V3, Bq);
      gemm_kernel<<<dim3(864, 1, 1), 256, 0, stream>>>(Bq, Afr, bias,
                                                       out + (size_t)b * NO * V3);
    }
  }
}

// Round 2
// 174.109 us; speedup vs baseline: 1.0794x; 1.0165x over previous
//
#include <hip/hip_runtime.h>
#include <stdint.h>

#define V3 110592        // 48*48*48
#define PLANE 2304       // 48*48
#define NO 64

typedef unsigned short ushort_t;
typedef __attribute__((ext_vector_type(8))) short short8v;
typedef __attribute__((ext_vector_type(4))) float float4v;

__device__ __forceinline__ uint32_t f2bf1(float f) {
  uint32_t u = __float_as_uint(f);
  u += 0x7FFFu + ((u >> 16) & 1u);   // RNE
  return u >> 16;
}
__device__ __forceinline__ uint32_t pack2(float a, float b) {
  return f2bf1(a) | (f2bf1(b) << 16);
}

// ---------- prep: Afr[g=kk/8][m][8] bf16, kk = dzi*192 + i*6 + qi ----------
__global__ void prep_kernel(const float* __restrict__ w, ushort_t* __restrict__ Afr) {
  int idx = blockIdx.x * 256 + threadIdx.x;     // 120*64*8 = 61440
  if (idx >= 120 * 64 * 8) return;
  int r = idx & 7, m = (idx >> 3) & 63, g = idx >> 9;
  int kk = g * 8 + r;
  int dzi = kk / 192, k2 = kk % 192;
  int i = k2 / 6, qi = k2 % 6;
  const int Q[6] = {0, 1, 2, 4, 5, 8};
  const int pidx[13] = {0, 1, 2, 3, 4, 5, 6, 0, 7, 8, 0, 0, 9};  // r2 -> shell
  int dz = dzi - 2;
  int p = pidx[Q[qi] + dz * dz];
  Afr[idx] = (ushort_t)f2bf1(0.28209479177387814f * w[(m * 32 + i) * 10 + p]);
}

// ---------- pass 1: per-plane 2D class sums; NO LDS, NO barriers ----------
// wave-autonomous: lanes = w (52 active incl. halo), shfl for dx, rolling regs
// for dy. Bq layout [G = d*24 + g][n][8] bf16, G-groups of 8 k' (k' = i*6+qi).
// R2: strips of 6 rows (10 iters incl. halo) instead of 12 (16 iters) ->
// 2x blocks (1536), 24 waves/CU (was 12). bq is latency-bound on the serial
// load->shfl->add chain per r-iteration; doubling TLP hides it. Cost: +25%
// x-load volume (28->35 MB), negligible vs the 85 MB Bq write stream.
__global__ __launch_bounds__(256) void bq_kernel(const float* __restrict__ x,
                                                 ushort_t* __restrict__ Bq) {
  const int tid = threadIdx.x;
  const int lane = tid & 63;
  const int strip = tid >> 6;                    // 0..3 within block
  const int d = blockIdx.x;                      // 0..47
  const int ig = blockIdx.y & 7;                 // 0..7 channel group
  const int half = blockIdx.y >> 3;              // 0..1 strip half
  const float* xb = x + (size_t)blockIdx.z * 32 * V3;
  ushort_t* Bqb = Bq + (size_t)blockIdx.z * ((size_t)1152 * PLANE * 8);

  const int h0 = (half * 4 + strip) * 6;         // 6-row strip base
  const int gw = lane - 2;
  const bool okw = (gw >= 0 && gw < 48);
  const int sl1 = lane > 0 ? lane - 1 : 0;
  const int sl2 = lane > 1 ? lane - 2 : 0;
  const int sr1 = lane < 63 ? lane + 1 : 63;
  const int sr2 = lane < 62 ? lane + 2 : 63;
  const bool okst = (lane >= 2 && lane <= 49);

  const float* px[4];
#pragma unroll
  for (int ii = 0; ii < 4; ++ii)
    px[ii] = xb + ((size_t)(ig * 4 + ii) * 48 + d) * PLANE + gw;

  float a0[4][5], s1[4][5], s4[4][5];            // rolling 5-row windows

#pragma unroll
  for (int r = 0; r < 10; ++r) {
    const int gh = h0 - 2 + r;
    const bool okv = okw && (gh >= 0) && (gh < 48);
    const int slot = r % 5;
#pragma unroll
    for (int ii = 0; ii < 4; ++ii) {
      float v = okv ? px[ii][gh * 48] : 0.f;
      float vl1 = __shfl(v, sl1);
      float vr1 = __shfl(v, sr1);
      float vl2 = __shfl(v, sl2);
      float vr2 = __shfl(v, sr2);
      a0[ii][slot] = v;                          // dx^2 = 0
      s1[ii][slot] = vl1 + vr1;                  // dx^2 = 1
      s4[ii][slot] = vl2 + vr2;                  // dx^2 = 4
    }
    if (r >= 4) {
      const int j0 = (r - 4) % 5, j1 = (r - 3) % 5, j2 = (r - 2) % 5,
                j3 = (r - 1) % 5, j4 = r % 5;    // j = dy offset 0..4
      uint32_t dw[12];
#pragma unroll
      for (int ii = 0; ii < 4; ++ii) {
        float B0 = a0[ii][j2];
        float B1 = s1[ii][j2] + a0[ii][j1] + a0[ii][j3];
        float B2 = s1[ii][j1] + s1[ii][j3];
        float B3 = s4[ii][j2] + a0[ii][j0] + a0[ii][j4];
        float B4 = s4[ii][j1] + s4[ii][j3] + s1[ii][j0] + s1[ii][j4];
        float B5 = s4[ii][j0] + s4[ii][j4];
        dw[ii * 3 + 0] = pack2(B0, B1);
        dw[ii * 3 + 1] = pack2(B2, B3);
        dw[ii * 3 + 2] = pack2(B4, B5);
      }
      if (okst) {
        const int n = (h0 + r - 4) * 48 + gw;
        const size_t gb = (size_t)(d * 24 + ig * 3);
        uint4 c0 = {dw[0], dw[1], dw[2], dw[3]};
        uint4 c1 = {dw[4], dw[5], dw[6], dw[7]};
        uint4 c2 = {dw[8], dw[9], dw[10], dw[11]};
        *(uint4*)(Bqb + ((gb + 0) * PLANE + n) * 8) = c0;
        *(uint4*)(Bqb + ((gb + 1) * PLANE + n) * 8) = c1;
        *(uint4*)(Bqb + ((gb + 2) * PLANE + n) * 8) = c2;
      }
    }
  }
}

// ---------- pass 2: plane-major GEMM, K = 960 linear walk, ping-pong frags ----------
// out[m][d,n] = sum_kk Afr[kk][m] * Bq[(d-2)*24 + kk/8][n][kk%8] + bias[m]
// XCD-aware partitioning: flat blockIdx b in [0,864); hardware round-robins
// b%8 across the 8 XCDs. Partition p = b&7 = (d_group<<1)|n_half owns
// d in [d_group*12, d_group*12+12) x n-half. Its Bq working set is 16 source
// half-planes (~7 MB) pinned to ONE XCD's L2, so each source plane's Bq is
// fetched ~once and reused by the 5 output d's that consume it. Verified R1:
// FETCH 207.8 -> 83.4 MB (= unique Bq), dur 70.5 -> 57.4 us.
__global__ __launch_bounds__(256) void gemm_kernel(const ushort_t* __restrict__ Bq,
                                                   const ushort_t* __restrict__ Afr,
                                                   const float* __restrict__ bias,
                                                   float* __restrict__ out) {
  const int tid = threadIdx.x;
  const int lane = tid & 63, wi = tid >> 6;
  const int quad = lane >> 4, m15 = lane & 15;
  const int b = blockIdx.x;                      // 0..863 flat
  const int p = b & 7;                           // XCD partition
  const int s = b >> 3;                          // 0..107 within partition
  const int dl = s / 9;                          // 0..11
  const int nbl = s - dl * 9;                    // 0..8
  const int d = (p >> 1) * 12 + dl;              // output plane
  const int n0 = ((p & 1) * 9 + nbl) * 128 + wi * 32;
  const ushort_t* Bqb = Bq + (size_t)blockIdx.z * ((size_t)1152 * PLANE * 8);
  float* outb = out + (size_t)blockIdx.z * (size_t)NO * V3;

  const int lo = (d < 2) ? (2 - d) : 0;          // dzi range [lo,hi]
  const int hi = (d > 45) ? (49 - d) : 4;
  const int kslo = 6 * lo;
  const int T = 6 * (hi - lo + 1);               // trips: 18/24/30, always even

  const ushort_t* ap = Afr + ((size_t)(kslo * 4 + quad) * 64 + m15) * 8;
  const ushort_t* bp = Bqb + ((size_t)((d - 2) * 24 + kslo * 4 + quad) * PLANE + n0 + m15) * 8;
  const int astep = 4 * 64 * 8;                  // shorts per ks
  const int bstep = 4 * PLANE * 8;

  float4v acc[4][2];
#pragma unroll
  for (int mt = 0; mt < 4; ++mt)
#pragma unroll
    for (int nt = 0; nt < 2; ++nt) acc[mt][nt] = (float4v){0.f, 0.f, 0.f, 0.f};

  short8v A0[4], B0[2], A1[4], B1[2];

#define LOADSET(Ax, Bx)                                                        \
  {                                                                            \
    _Pragma("unroll") for (int nt = 0; nt < 2; ++nt)                           \
        Bx[nt] = *(const short8v*)(bp + nt * 128);                             \
    _Pragma("unroll") for (int mt = 0; mt < 4; ++mt)                           \
        Ax[mt] = *(const short8v*)(ap + mt * 128);                             \
    ap += astep; bp += bstep;                                                  \
  }
#define MFMASET(Ax, Bx)                                                        \
  {                                                                            \
    _Pragma("unroll") for (int mt = 0; mt < 4; ++mt)                           \
        _Pragma("unroll") for (int nt = 0; nt < 2; ++nt)                       \
            acc[mt][nt] = __builtin_amdgcn_mfma_f32_16x16x32_bf16(             \
                Ax[mt], Bx[nt], acc[mt][nt], 0, 0, 0);                         \
  }

  LOADSET(A0, B0);
  for (int k = 1; k + 1 < T; k += 2) {
    LOADSET(A1, B1);
    MFMASET(A0, B0);
    LOADSET(A0, B0);
    MFMASET(A1, B1);
  }
  LOADSET(A1, B1);
  MFMASET(A0, B0);
  MFMASET(A1, B1);
#undef LOADSET
#undef MFMASET

  // C/D: col(n) = lane&15, row(m) = quad*4 + reg
  const int vb = d * PLANE + n0 + m15;
#pragma unroll
  for (int mt = 0; mt < 4; ++mt) {
#pragma unroll
    for (int r = 0; r < 4; ++r) {
      int m = mt * 16 + quad * 4 + r;
      float bv = bias[m];
      float* op = outb + (size_t)m * V3 + vb;
#pragma unroll
      for (int nt = 0; nt < 2; ++nt)
        op[nt * 16] = acc[mt][nt][r] + bv;
    }
  }
}

extern "C" void kernel_launch(void* const* d_in, const int* in_sizes, int n_in,
                              void* d_out, int out_size, void* d_ws, size_t ws_size,
                              hipStream_t stream) {
  const float* x    = (const float*)d_in[0];   // [2,32,1,48,48,48]
  const float* w    = (const float*)d_in[1];   // [64,32,1,1,1,10]
  const float* bias = (const float*)d_in[2];   // [64]
  float* out = (float*)d_out;                  // [2,64,1,48,48,48]

  ushort_t* Afr = (ushort_t*)d_ws;                         // 122880 B
  ushort_t* Bq  = (ushort_t*)((char*)d_ws + 131072);
  const size_t SB = (size_t)1152 * PLANE * 8 * 2;          // 42.5 MB per batch
  const bool both = (ws_size >= 131072 + 2 * SB);

  prep_kernel<<<240, 256, 0, stream>>>(w, Afr);
  if (both) {
    bq_kernel<<<dim3(48, 16, 2), 256, 0, stream>>>(x, Bq);
    gemm_kernel<<<dim3(864, 1, 2), 256, 0, stream>>>(Bq, Afr, bias, out);
  } else {
    for (int b = 0; b < 2; ++b) {
      bq_kernel<<<dim3(48, 16, 1), 256, 0, stream>>>(x + (size_t)b * 32 * V3, Bq);
      gemm_kernel<<<dim3(864, 1, 1), 256, 0, stream>>>(Bq, Afr, bias,
                                                       out + (size_t)b * NO * V3);
    }
  }
}

// Round 3
// 171.529 us; speedup vs baseline: 1.0957x; 1.0150x over previous
//
#include <hip/hip_runtime.h>
#include <stdint.h>

#define V3 110592        // 48*48*48
#define PLANE 2304       // 48*48
#define NO 64

typedef unsigned short ushort_t;
typedef __attribute__((ext_vector_type(8))) short short8v;
typedef __attribute__((ext_vector_type(4))) float float4v;

__device__ __forceinline__ uint32_t f2bf1(float f) {
  uint32_t u = __float_as_uint(f);
  u += 0x7FFFu + ((u >> 16) & 1u);   // RNE
  return u >> 16;
}
__device__ __forceinline__ uint32_t pack2(float a, float b) {
  return f2bf1(a) | (f2bf1(b) << 16);
}

// ---------- prep: Afr[g=kk/8][m][8] bf16, kk = dzi*192 + i*6 + qi ----------
__global__ void prep_kernel(const float* __restrict__ w, ushort_t* __restrict__ Afr) {
  int idx = blockIdx.x * 256 + threadIdx.x;     // 120*64*8 = 61440
  if (idx >= 120 * 64 * 8) return;
  int r = idx & 7, m = (idx >> 3) & 63, g = idx >> 9;
  int kk = g * 8 + r;
  int dzi = kk / 192, k2 = kk % 192;
  int i = k2 / 6, qi = k2 % 6;
  const int Q[6] = {0, 1, 2, 4, 5, 8};
  const int pidx[13] = {0, 1, 2, 3, 4, 5, 6, 0, 7, 8, 0, 0, 9};  // r2 -> shell
  int dz = dzi - 2;
  int p = pidx[Q[qi] + dz * dz];
  Afr[idx] = (ushort_t)f2bf1(0.28209479177387814f * w[(m * 32 + i) * 10 + p]);
}

// ---------- pass 1: per-plane 2D class sums; NO LDS, NO barriers ----------
// wave-autonomous: lanes = w (52 active incl. halo), shfl for dx, rolling regs
// for dy. Bq layout [G = d*24 + g][n][8] bf16, G-groups of 8 k' (k' = i*6+qi).
// R2: 6-row strips, 1536 blocks, 24 waves/CU. (~neutral vs 12-row; kept.)
__global__ __launch_bounds__(256) void bq_kernel(const float* __restrict__ x,
                                                 ushort_t* __restrict__ Bq) {
  const int tid = threadIdx.x;
  const int lane = tid & 63;
  const int strip = tid >> 6;                    // 0..3 within block
  const int d = blockIdx.x;                      // 0..47
  const int ig = blockIdx.y & 7;                 // 0..7 channel group
  const int half = blockIdx.y >> 3;              // 0..1 strip half
  const float* xb = x + (size_t)blockIdx.z * 32 * V3;
  ushort_t* Bqb = Bq + (size_t)blockIdx.z * ((size_t)1152 * PLANE * 8);

  const int h0 = (half * 4 + strip) * 6;         // 6-row strip base
  const int gw = lane - 2;
  const bool okw = (gw >= 0 && gw < 48);
  const int sl1 = lane > 0 ? lane - 1 : 0;
  const int sl2 = lane > 1 ? lane - 2 : 0;
  const int sr1 = lane < 63 ? lane + 1 : 63;
  const int sr2 = lane < 62 ? lane + 2 : 63;
  const bool okst = (lane >= 2 && lane <= 49);

  const float* px[4];
#pragma unroll
  for (int ii = 0; ii < 4; ++ii)
    px[ii] = xb + ((size_t)(ig * 4 + ii) * 48 + d) * PLANE + gw;

  float a0[4][5], s1[4][5], s4[4][5];            // rolling 5-row windows

#pragma unroll
  for (int r = 0; r < 10; ++r) {
    const int gh = h0 - 2 + r;
    const bool okv = okw && (gh >= 0) && (gh < 48);
    const int slot = r % 5;
#pragma unroll
    for (int ii = 0; ii < 4; ++ii) {
      float v = okv ? px[ii][gh * 48] : 0.f;
      float vl1 = __shfl(v, sl1);
      float vr1 = __shfl(v, sr1);
      float vl2 = __shfl(v, sl2);
      float vr2 = __shfl(v, sr2);
      a0[ii][slot] = v;                          // dx^2 = 0
      s1[ii][slot] = vl1 + vr1;                  // dx^2 = 1
      s4[ii][slot] = vl2 + vr2;                  // dx^2 = 4
    }
    if (r >= 4) {
      const int j0 = (r - 4) % 5, j1 = (r - 3) % 5, j2 = (r - 2) % 5,
                j3 = (r - 1) % 5, j4 = r % 5;    // j = dy offset 0..4
      uint32_t dw[12];
#pragma unroll
      for (int ii = 0; ii < 4; ++ii) {
        float B0 = a0[ii][j2];
        float B1 = s1[ii][j2] + a0[ii][j1] + a0[ii][j3];
        float B2 = s1[ii][j1] + s1[ii][j3];
        float B3 = s4[ii][j2] + a0[ii][j0] + a0[ii][j4];
        float B4 = s4[ii][j1] + s4[ii][j3] + s1[ii][j0] + s1[ii][j4];
        float B5 = s4[ii][j0] + s4[ii][j4];
        dw[ii * 3 + 0] = pack2(B0, B1);
        dw[ii * 3 + 1] = pack2(B2, B3);
        dw[ii * 3 + 2] = pack2(B4, B5);
      }
      if (okst) {
        const int n = (h0 + r - 4) * 48 + gw;
        const size_t gb = (size_t)(d * 24 + ig * 3);
        uint4 c0 = {dw[0], dw[1], dw[2], dw[3]};
        uint4 c1 = {dw[4], dw[5], dw[6], dw[7]};
        uint4 c2 = {dw[8], dw[9], dw[10], dw[11]};
        *(uint4*)(Bqb + ((gb + 0) * PLANE + n) * 8) = c0;
        *(uint4*)(Bqb + ((gb + 1) * PLANE + n) * 8) = c1;
        *(uint4*)(Bqb + ((gb + 2) * PLANE + n) * 8) = c2;
      }
    }
  }
}

// ---------- pass 2: plane-major GEMM, K = 960 linear walk ----------
// out[m][d,n] = sum_kk Afr[kk][m] * Bq[(d-2)*24 + kk/8][n][kk%8] + bias[m]
// XCD partition (verified R1: FETCH 207.8 -> 83.4 MB): b&7 -> XCD, owns
// (d_group, n_half); per-XCD Bq working set ~2.6 MB rolling -> L2-resident.
// R3: depth-3 register pipeline (triple-buffered loadsets, unroll-3; T is
// always a multiple of 3). Was depth-1 ping-pong: per-SIMD hiding capacity
// 3.4 waves x 38 MFMA-cyc = 130 cyc vs ~400-cyc avg B-load latency ->
// latency-bound (MfmaUtil 17.7%). Depth-3 keeps 2 trips (12 loads) in
// flight ahead of each MFMA set. VGPR ~120 < 128 -> no occupancy loss.
__global__ __launch_bounds__(256) void gemm_kernel(const ushort_t* __restrict__ Bq,
                                                   const ushort_t* __restrict__ Afr,
                                                   const float* __restrict__ bias,
                                                   float* __restrict__ out) {
  const int tid = threadIdx.x;
  const int lane = tid & 63, wi = tid >> 6;
  const int quad = lane >> 4, m15 = lane & 15;
  const int b = blockIdx.x;                      // 0..863 flat
  const int p = b & 7;                           // XCD partition
  const int s = b >> 3;                          // 0..107 within partition
  const int dl = s / 9;                          // 0..11
  const int nbl = s - dl * 9;                    // 0..8
  const int d = (p >> 1) * 12 + dl;              // output plane
  const int n0 = ((p & 1) * 9 + nbl) * 128 + wi * 32;
  const ushort_t* Bqb = Bq + (size_t)blockIdx.z * ((size_t)1152 * PLANE * 8);
  float* outb = out + (size_t)blockIdx.z * (size_t)NO * V3;

  const int lo = (d < 2) ? (2 - d) : 0;          // dzi range [lo,hi]
  const int hi = (d > 45) ? (49 - d) : 4;
  const int kslo = 6 * lo;
  const int T = 6 * (hi - lo + 1);               // trips: 18/24/30 (mult of 6)

  const ushort_t* ap = Afr + ((size_t)(kslo * 4 + quad) * 64 + m15) * 8;
  const ushort_t* bp = Bqb + ((size_t)((d - 2) * 24 + kslo * 4 + quad) * PLANE + n0 + m15) * 8;
  const int astep = 4 * 64 * 8;                  // shorts per ks
  const int bstep = 4 * PLANE * 8;

  float4v acc[4][2];
#pragma unroll
  for (int mt = 0; mt < 4; ++mt)
#pragma unroll
    for (int nt = 0; nt < 2; ++nt) acc[mt][nt] = (float4v){0.f, 0.f, 0.f, 0.f};

  short8v A0[4], B0[2], A1[4], B1[2], A2[4], B2[2];

#define LOADSET(Ax, Bx)                                                        \
  {                                                                            \
    _Pragma("unroll") for (int nt = 0; nt < 2; ++nt)                           \
        Bx[nt] = *(const short8v*)(bp + nt * 128);                             \
    _Pragma("unroll") for (int mt = 0; mt < 4; ++mt)                           \
        Ax[mt] = *(const short8v*)(ap + mt * 128);                             \
    ap += astep; bp += bstep;                                                  \
  }
#define MFMASET(Ax, Bx)                                                        \
  {                                                                            \
    _Pragma("unroll") for (int mt = 0; mt < 4; ++mt)                           \
        _Pragma("unroll") for (int nt = 0; nt < 2; ++nt)                       \
            acc[mt][nt] = __builtin_amdgcn_mfma_f32_16x16x32_bf16(             \
                Ax[mt], Bx[nt], acc[mt][nt], 0, 0, 0);                         \
  }

  // depth-3 rotation: trips load in order; buffer = trip % 3.
  LOADSET(A0, B0);                               // trip 0
  LOADSET(A1, B1);                               // trip 1
  for (int k = 0; k < T - 3; k += 3) {
    LOADSET(A2, B2);                             // trip k+2
    MFMASET(A0, B0);                             // trip k
    LOADSET(A0, B0);                             // trip k+3
    MFMASET(A1, B1);                             // trip k+1
    LOADSET(A1, B1);                             // trip k+4
    MFMASET(A2, B2);                             // trip k+2
  }
  LOADSET(A2, B2);                               // trip T-1
  MFMASET(A0, B0);                               // trip T-3
  MFMASET(A1, B1);                               // trip T-2
  MFMASET(A2, B2);                               // trip T-1
#undef LOADSET
#undef MFMASET

  // C/D: col(n) = lane&15, row(m) = quad*4 + reg
  const int vb = d * PLANE + n0 + m15;
#pragma unroll
  for (int mt = 0; mt < 4; ++mt) {
#pragma unroll
    for (int r = 0; r < 4; ++r) {
      int m = mt * 16 + quad * 4 + r;
      float bv = bias[m];
      float* op = outb + (size_t)m * V3 + vb;
#pragma unroll
      for (int nt = 0; nt < 2; ++nt)
        op[nt * 16] = acc[mt][nt][r] + bv;
    }
  }
}

extern "C" void kernel_launch(void* const* d_in, const int* in_sizes, int n_in,
                              void* d_out, int out_size, void* d_ws, size_t ws_size,
                              hipStream_t stream) {
  const float* x    = (const float*)d_in[0];   // [2,32,1,48,48,48]
  const float* w    = (const float*)d_in[1];   // [64,32,1,1,1,10]
  const float* bias = (const float*)d_in[2];   // [64]
  float* out = (float*)d_out;                  // [2,64,1,48,48,48]

  ushort_t* Afr = (ushort_t*)d_ws;                         // 122880 B
  ushort_t* Bq  = (ushort_t*)((char*)d_ws + 131072);
  const size_t SB = (size_t)1152 * PLANE * 8 * 2;          // 42.5 MB per batch
  const bool both = (ws_size >= 131072 + 2 * SB);

  prep_kernel<<<240, 256, 0, stream>>>(w, Afr);
  if (both) {
    bq_kernel<<<dim3(48, 16, 2), 256, 0, stream>>>(x, Bq);
    gemm_kernel<<<dim3(864, 1, 2), 256, 0, stream>>>(Bq, Afr, bias, out);
  } else {
    for (int b = 0; b < 2; ++b) {
      bq_kernel<<<dim3(48, 16, 1), 256, 0, stream>>>(x + (size_t)b * 32 * V3, Bq);
      gemm_kernel<<<dim3(864, 1, 1), 256, 0, stream>>>(Bq, Afr, bias,
                                                       out + (size_t)b * NO * V3);
    }
  }
}

// Round 4
// 150.632 us; speedup vs baseline: 1.2477x; 1.1387x over previous
//
#include <hip/hip_runtime.h>
#include <stdint.h>

#define V3 110592        // 48*48*48
#define PLANE 2304       // 48*48
#define NO 64

typedef unsigned short ushort_t;
typedef __attribute__((ext_vector_type(8))) short short8v;
typedef __attribute__((ext_vector_type(4))) float float4v;

__device__ __forceinline__ uint32_t f2bf1(float f) {
  uint32_t u = __float_as_uint(f);
  u += 0x7FFFu + ((u >> 16) & 1u);   // RNE
  return u >> 16;
}
__device__ __forceinline__ uint32_t pack2(float a, float b) {
  return f2bf1(a) | (f2bf1(b) << 16);
}

// ---------- prep: Afr[g=kk/8][m][8] bf16, kk = dzi*192 + i*6 + qi ----------
__global__ void prep_kernel(const float* __restrict__ w, ushort_t* __restrict__ Afr) {
  int idx = blockIdx.x * 256 + threadIdx.x;     // 120*64*8 = 61440
  if (idx >= 120 * 64 * 8) return;
  int r = idx & 7, m = (idx >> 3) & 63, g = idx >> 9;
  int kk = g * 8 + r;
  int dzi = kk / 192, k2 = kk % 192;
  int i = k2 / 6, qi = k2 % 6;
  const int Q[6] = {0, 1, 2, 4, 5, 8};
  const int pidx[13] = {0, 1, 2, 3, 4, 5, 6, 0, 7, 8, 0, 0, 9};  // r2 -> shell
  int dz = dzi - 2;
  int p = pidx[Q[qi] + dz * dz];
  Afr[idx] = (ushort_t)f2bf1(0.28209479177387814f * w[(m * 32 + i) * 10 + p]);
}

// ---------- pass 1: per-plane 2D class sums; NO LDS, NO barriers ----------
// R4: two-phase — issue ALL 40 independent x-loads into v[10][4] first, then
// the shfl/reduce/store sweep. Previous single-phase collapsed to serial
// load->use (VGPR_Count 56 under default 8-wave occupancy targeting).
// __launch_bounds__(256,4) raises the VGPR cap to 128 so v[] stays resident.
__global__ __launch_bounds__(256, 4) void bq_kernel(const float* __restrict__ x,
                                                    ushort_t* __restrict__ Bq) {
  const int tid = threadIdx.x;
  const int lane = tid & 63;
  const int strip = tid >> 6;                    // 0..3 within block
  const int d = blockIdx.x;                      // 0..47
  const int ig = blockIdx.y & 7;                 // 0..7 channel group
  const int half = blockIdx.y >> 3;              // 0..1 strip half
  const float* xb = x + (size_t)blockIdx.z * 32 * V3;
  ushort_t* Bqb = Bq + (size_t)blockIdx.z * ((size_t)1152 * PLANE * 8);

  const int h0 = (half * 4 + strip) * 6;         // 6-row strip base
  const int gw = lane - 2;
  const bool okw = (gw >= 0 && gw < 48);
  const int sl1 = lane > 0 ? lane - 1 : 0;
  const int sl2 = lane > 1 ? lane - 2 : 0;
  const int sr1 = lane < 63 ? lane + 1 : 63;
  const int sr2 = lane < 62 ? lane + 2 : 63;
  const bool okst = (lane >= 2 && lane <= 49);

  const float* px[4];
#pragma unroll
  for (int ii = 0; ii < 4; ++ii)
    px[ii] = xb + ((size_t)(ig * 4 + ii) * 48 + d) * PLANE + gw;

  // phase 1: all loads in flight (independent addresses, one vmcnt chain)
  float v[10][4];
#pragma unroll
  for (int r = 0; r < 10; ++r) {
    const int gh = h0 - 2 + r;
    const bool okv = okw && (gh >= 0) && (gh < 48);
#pragma unroll
    for (int ii = 0; ii < 4; ++ii)
      v[r][ii] = okv ? px[ii][gh * 48] : 0.f;
  }

  // phase 2: shfl class-sums with rolling windows; a0 terms read v[] directly
  float s1[4][5], s4[4][5];
#pragma unroll
  for (int r = 0; r < 10; ++r) {
    const int slot = r % 5;
#pragma unroll
    for (int ii = 0; ii < 4; ++ii) {
      float val = v[r][ii];
      float vl1 = __shfl(val, sl1);
      float vr1 = __shfl(val, sr1);
      float vl2 = __shfl(val, sl2);
      float vr2 = __shfl(val, sr2);
      s1[ii][slot] = vl1 + vr1;                  // dx^2 = 1
      s4[ii][slot] = vl2 + vr2;                  // dx^2 = 4
    }
    if (r >= 4) {
      const int j0 = (r - 4) % 5, j1 = (r - 3) % 5, j2 = (r - 2) % 5,
                j3 = (r - 1) % 5, j4 = r % 5;    // j = dy offset 0..4
      uint32_t dw[12];
#pragma unroll
      for (int ii = 0; ii < 4; ++ii) {
        float B0 = v[r - 2][ii];
        float B1 = s1[ii][j2] + v[r - 3][ii] + v[r - 1][ii];
        float B2 = s1[ii][j1] + s1[ii][j3];
        float B3 = s4[ii][j2] + v[r - 4][ii] + v[r][ii];
        float B4 = s4[ii][j1] + s4[ii][j3] + s1[ii][j0] + s1[ii][j4];
        float B5 = s4[ii][j0] + s4[ii][j4];
        dw[ii * 3 + 0] = pack2(B0, B1);
        dw[ii * 3 + 1] = pack2(B2, B3);
        dw[ii * 3 + 2] = pack2(B4, B5);
      }
      if (okst) {
        const int n = (h0 + r - 4) * 48 + gw;
        const size_t gb = (size_t)(d * 24 + ig * 3);
        uint4 c0 = {dw[0], dw[1], dw[2], dw[3]};
        uint4 c1 = {dw[4], dw[5], dw[6], dw[7]};
        uint4 c2 = {dw[8], dw[9], dw[10], dw[11]};
        *(uint4*)(Bqb + ((gb + 0) * PLANE + n) * 8) = c0;
        *(uint4*)(Bqb + ((gb + 1) * PLANE + n) * 8) = c1;
        *(uint4*)(Bqb + ((gb + 2) * PLANE + n) * 8) = c2;
      }
    }
  }
}

// ---------- pass 2: plane-major GEMM, K = 960 linear walk ----------
// out[m][d,n] = sum_kk Afr[kk][m] * Bq[(d-2)*24 + kk/8][n][kk%8] + bias[m]
// XCD partition (verified R1: FETCH 207.8 -> 83.4 MB): b&7 -> XCD, owns
// (d_group, n_half); per-XCD Bq working set rolling -> L2-resident.
// R4: __launch_bounds__(256,4) -> 128-VGPR cap. R3's depth-3 rotation needs
// ~120 VGPRs; under the default 64-VGPR cap the compiler provably collapsed
// it (VGPR_Count=64 -> ~1 loadset in flight, MfmaUtil 19%). With 4 waves/SIMD
// resident (grid supplies 6.75) and 2 trips of loads in flight, load latency
// (~300cy) is covered by 2x38 MFMA-cyc x 4 waves.
__global__ __launch_bounds__(256, 4) void gemm_kernel(const ushort_t* __restrict__ Bq,
                                                      const ushort_t* __restrict__ Afr,
                                                      const float* __restrict__ bias,
                                                      float* __restrict__ out) {
  const int tid = threadIdx.x;
  const int lane = tid & 63, wi = tid >> 6;
  const int quad = lane >> 4, m15 = lane & 15;
  const int b = blockIdx.x;                      // 0..863 flat
  const int p = b & 7;                           // XCD partition
  const int s = b >> 3;                          // 0..107 within partition
  const int dl = s / 9;                          // 0..11
  const int nbl = s - dl * 9;                    // 0..8
  const int d = (p >> 1) * 12 + dl;              // output plane
  const int n0 = ((p & 1) * 9 + nbl) * 128 + wi * 32;
  const ushort_t* Bqb = Bq + (size_t)blockIdx.z * ((size_t)1152 * PLANE * 8);
  float* outb = out + (size_t)blockIdx.z * (size_t)NO * V3;

  const int lo = (d < 2) ? (2 - d) : 0;          // dzi range [lo,hi]
  const int hi = (d > 45) ? (49 - d) : 4;
  const int kslo = 6 * lo;
  const int T = 6 * (hi - lo + 1);               // trips: 18/24/30 (mult of 6)

  const ushort_t* ap = Afr + ((size_t)(kslo * 4 + quad) * 64 + m15) * 8;
  const ushort_t* bp = Bqb + ((size_t)((d - 2) * 24 + kslo * 4 + quad) * PLANE + n0 + m15) * 8;
  const int astep = 4 * 64 * 8;                  // shorts per ks
  const int bstep = 4 * PLANE * 8;

  float4v acc[4][2];
#pragma unroll
  for (int mt = 0; mt < 4; ++mt)
#pragma unroll
    for (int nt = 0; nt < 2; ++nt) acc[mt][nt] = (float4v){0.f, 0.f, 0.f, 0.f};

  short8v A0[4], B0[2], A1[4], B1[2], A2[4], B2[2];

#define LOADSET(Ax, Bx)                                                        \
  {                                                                            \
    _Pragma("unroll") for (int nt = 0; nt < 2; ++nt)                           \
        Bx[nt] = *(const short8v*)(bp + nt * 128);                             \
    _Pragma("unroll") for (int mt = 0; mt < 4; ++mt)                           \
        Ax[mt] = *(const short8v*)(ap + mt * 128);                             \
    ap += astep; bp += bstep;                                                  \
  }
#define MFMASET(Ax, Bx)                                                        \
  {                                                                            \
    _Pragma("unroll") for (int mt = 0; mt < 4; ++mt)                           \
        _Pragma("unroll") for (int nt = 0; nt < 2; ++nt)                       \
            acc[mt][nt] = __builtin_amdgcn_mfma_f32_16x16x32_bf16(             \
                Ax[mt], Bx[nt], acc[mt][nt], 0, 0, 0);                         \
  }

  // depth-3 rotation: trips load in order; buffer = trip % 3.
  LOADSET(A0, B0);                               // trip 0
  LOADSET(A1, B1);                               // trip 1
  for (int k = 0; k < T - 3; k += 3) {
    LOADSET(A2, B2);                             // trip k+2
    MFMASET(A0, B0);                             // trip k
    LOADSET(A0, B0);                             // trip k+3
    MFMASET(A1, B1);                             // trip k+1
    LOADSET(A1, B1);                             // trip k+4
    MFMASET(A2, B2);                             // trip k+2
  }
  LOADSET(A2, B2);                               // trip T-1
  MFMASET(A0, B0);                               // trip T-3
  MFMASET(A1, B1);                               // trip T-2
  MFMASET(A2, B2);                               // trip T-1
#undef LOADSET
#undef MFMASET

  // C/D: col(n) = lane&15, row(m) = quad*4 + reg
  const int vb = d * PLANE + n0 + m15;
#pragma unroll
  for (int mt = 0; mt < 4; ++mt) {
#pragma unroll
    for (int r = 0; r < 4; ++r) {
      int m = mt * 16 + quad * 4 + r;
      float bv = bias[m];
      float* op = outb + (size_t)m * V3 + vb;
#pragma unroll
      for (int nt = 0; nt < 2; ++nt)
        op[nt * 16] = acc[mt][nt][r] + bv;
    }
  }
}

extern "C" void kernel_launch(void* const* d_in, const int* in_sizes, int n_in,
                              void* d_out, int out_size, void* d_ws, size_t ws_size,
                              hipStream_t stream) {
  const float* x    = (const float*)d_in[0];   // [2,32,1,48,48,48]
  const float* w    = (const float*)d_in[1];   // [64,32,1,1,1,10]
  const float* bias = (const float*)d_in[2];   // [64]
  float* out = (float*)d_out;                  // [2,64,1,48,48,48]

  ushort_t* Afr = (ushort_t*)d_ws;                         // 122880 B
  ushort_t* Bq  = (ushort_t*)((char*)d_ws + 131072);
  const size_t SB = (size_t)1152 * PLANE * 8 * 2;          // 42.5 MB per batch
  const bool both = (ws_size >= 131072 + 2 * SB);

  prep_kernel<<<240, 256, 0, stream>>>(w, Afr);
  if (both) {
    bq_kernel<<<dim3(48, 16, 2), 256, 0, stream>>>(x, Bq);
    gemm_kernel<<<dim3(864, 1, 2), 256, 0, stream>>>(Bq, Afr, bias, out);
  } else {
    for (int b = 0; b < 2; ++b) {
      bq_kernel<<<dim3(48, 16, 1), 256, 0, stream>>>(x + (size_t)b * 32 * V3, Bq);
      gemm_kernel<<<dim3(864, 1, 1), 256, 0, stream>>>(Bq, Afr, bias,
                                                       out + (size_t)b * NO * V3);
    }
  }
}

// Round 5
// 150.330 us; speedup vs baseline: 1.2502x; 1.0020x over previous
//
#include <hip/hip_runtime.h>
#include <stdint.h>

#define V3 110592        // 48*48*48
#define PLANE 2304       // 48*48
#define NO 64

typedef unsigned short ushort_t;
typedef __attribute__((ext_vector_type(8))) short short8v;
typedef __attribute__((ext_vector_type(4))) float float4v;

__device__ __forceinline__ uint32_t f2bf1(float f) {
  uint32_t u = __float_as_uint(f);
  u += 0x7FFFu + ((u >> 16) & 1u);   // RNE
  return u >> 16;
}
__device__ __forceinline__ uint32_t pack2(float a, float b) {
  return f2bf1(a) | (f2bf1(b) << 16);
}

// ---------- prep: Afr[g=kk/8][m][8] bf16, kk = dzi*192 + i*6 + qi ----------
__global__ void prep_kernel(const float* __restrict__ w, ushort_t* __restrict__ Afr) {
  int idx = blockIdx.x * 256 + threadIdx.x;     // 120*64*8 = 61440
  if (idx >= 120 * 64 * 8) return;
  int r = idx & 7, m = (idx >> 3) & 63, g = idx >> 9;
  int kk = g * 8 + r;
  int dzi = kk / 192, k2 = kk % 192;
  int i = k2 / 6, qi = k2 % 6;
  const int Q[6] = {0, 1, 2, 4, 5, 8};
  const int pidx[13] = {0, 1, 2, 3, 4, 5, 6, 0, 7, 8, 0, 0, 9};  // r2 -> shell
  int dz = dzi - 2;
  int p = pidx[Q[qi] + dz * dz];
  Afr[idx] = (ushort_t)f2bf1(0.28209479177387814f * w[(m * 32 + i) * 10 + p]);
}

// ---------- pass 1: per-plane 2D class sums; NO LDS, NO barriers ----------
// R4 (verified): two-phase (all 40 loads first, then shfl/reduce/store) took
// bq to ~its memory floor (~16-18 us). Kept as-is.
__global__ __launch_bounds__(256, 4) void bq_kernel(const float* __restrict__ x,
                                                    ushort_t* __restrict__ Bq) {
  const int tid = threadIdx.x;
  const int lane = tid & 63;
  const int strip = tid >> 6;                    // 0..3 within block
  const int d = blockIdx.x;                      // 0..47
  const int ig = blockIdx.y & 7;                 // 0..7 channel group
  const int half = blockIdx.y >> 3;              // 0..1 strip half
  const float* xb = x + (size_t)blockIdx.z * 32 * V3;
  ushort_t* Bqb = Bq + (size_t)blockIdx.z * ((size_t)1152 * PLANE * 8);

  const int h0 = (half * 4 + strip) * 6;         // 6-row strip base
  const int gw = lane - 2;
  const bool okw = (gw >= 0 && gw < 48);
  const int sl1 = lane > 0 ? lane - 1 : 0;
  const int sl2 = lane > 1 ? lane - 2 : 0;
  const int sr1 = lane < 63 ? lane + 1 : 63;
  const int sr2 = lane < 62 ? lane + 2 : 63;
  const bool okst = (lane >= 2 && lane <= 49);

  const float* px[4];
#pragma unroll
  for (int ii = 0; ii < 4; ++ii)
    px[ii] = xb + ((size_t)(ig * 4 + ii) * 48 + d) * PLANE + gw;

  // phase 1: all loads in flight (independent addresses, one vmcnt chain)
  float v[10][4];
#pragma unroll
  for (int r = 0; r < 10; ++r) {
    const int gh = h0 - 2 + r;
    const bool okv = okw && (gh >= 0) && (gh < 48);
#pragma unroll
    for (int ii = 0; ii < 4; ++ii)
      v[r][ii] = okv ? px[ii][gh * 48] : 0.f;
  }

  // phase 2: shfl class-sums with rolling windows; a0 terms read v[] directly
  float s1[4][5], s4[4][5];
#pragma unroll
  for (int r = 0; r < 10; ++r) {
    const int slot = r % 5;
#pragma unroll
    for (int ii = 0; ii < 4; ++ii) {
      float val = v[r][ii];
      float vl1 = __shfl(val, sl1);
      float vr1 = __shfl(val, sr1);
      float vl2 = __shfl(val, sl2);
      float vr2 = __shfl(val, sr2);
      s1[ii][slot] = vl1 + vr1;                  // dx^2 = 1
      s4[ii][slot] = vl2 + vr2;                  // dx^2 = 4
    }
    if (r >= 4) {
      const int j0 = (r - 4) % 5, j1 = (r - 3) % 5, j2 = (r - 2) % 5,
                j3 = (r - 1) % 5, j4 = r % 5;    // j = dy offset 0..4
      uint32_t dw[12];
#pragma unroll
      for (int ii = 0; ii < 4; ++ii) {
        float B0 = v[r - 2][ii];
        float B1 = s1[ii][j2] + v[r - 3][ii] + v[r - 1][ii];
        float B2 = s1[ii][j1] + s1[ii][j3];
        float B3 = s4[ii][j2] + v[r - 4][ii] + v[r][ii];
        float B4 = s4[ii][j1] + s4[ii][j3] + s1[ii][j0] + s1[ii][j4];
        float B5 = s4[ii][j0] + s4[ii][j4];
        dw[ii * 3 + 0] = pack2(B0, B1);
        dw[ii * 3 + 1] = pack2(B2, B3);
        dw[ii * 3 + 2] = pack2(B4, B5);
      }
      if (okst) {
        const int n = (h0 + r - 4) * 48 + gw;
        const size_t gb = (size_t)(d * 24 + ig * 3);
        uint4 c0 = {dw[0], dw[1], dw[2], dw[3]};
        uint4 c1 = {dw[4], dw[5], dw[6], dw[7]};
        uint4 c2 = {dw[8], dw[9], dw[10], dw[11]};
        *(uint4*)(Bqb + ((gb + 0) * PLANE + n) * 8) = c0;
        *(uint4*)(Bqb + ((gb + 1) * PLANE + n) * 8) = c1;
        *(uint4*)(Bqb + ((gb + 2) * PLANE + n) * 8) = c2;
      }
    }
  }
}

// ---------- pass 2: plane-major GEMM, K = 960 linear walk ----------
// out[m][d,n] = sum_kk Afr[kk][m] * Bq[(d-2)*24 + kk/8][n][kk%8] + bias[m]
// XCD partition (verified R1: FETCH 207.8 -> 83.4 MB): b&7 -> XCD.
// R5: sched_barrier(0)-pinned depth-3 pipeline. R3/R4 showed the pre-RA
// scheduler collapses the rotation regardless of the VGPR cap (VGPR_Count
// 56-64, ~1 loadset in flight, MfmaUtil ~18%). Pinning each LOADSET/MFMASET
// boundary forces 3 live buffers (~116 VGPR < 128 cap) and lets the waitcnt
// pass emit counted vmcnt(12) (2 loadsets outstanding) instead of a drain.
// s_setprio(1) around MFMA: waves here are barrier-free + phase-staggered
// (the T5-pays regime); worst case measured elsewhere was -1.5%.
__global__ __launch_bounds__(256, 4) void gemm_kernel(const ushort_t* __restrict__ Bq,
                                                      const ushort_t* __restrict__ Afr,
                                                      const float* __restrict__ bias,
                                                      float* __restrict__ out) {
  const int tid = threadIdx.x;
  const int lane = tid & 63, wi = tid >> 6;
  const int quad = lane >> 4, m15 = lane & 15;
  const int b = blockIdx.x;                      // 0..863 flat
  const int p = b & 7;                           // XCD partition
  const int s = b >> 3;                          // 0..107 within partition
  const int dl = s / 9;                          // 0..11
  const int nbl = s - dl * 9;                    // 0..8
  const int d = (p >> 1) * 12 + dl;              // output plane
  const int n0 = ((p & 1) * 9 + nbl) * 128 + wi * 32;
  const ushort_t* Bqb = Bq + (size_t)blockIdx.z * ((size_t)1152 * PLANE * 8);
  float* outb = out + (size_t)blockIdx.z * (size_t)NO * V3;

  const int lo = (d < 2) ? (2 - d) : 0;          // dzi range [lo,hi]
  const int hi = (d > 45) ? (49 - d) : 4;
  const int kslo = 6 * lo;
  const int T = 6 * (hi - lo + 1);               // trips: 18/24/30 (mult of 6)

  const ushort_t* ap = Afr + ((size_t)(kslo * 4 + quad) * 64 + m15) * 8;
  const ushort_t* bp = Bqb + ((size_t)((d - 2) * 24 + kslo * 4 + quad) * PLANE + n0 + m15) * 8;
  const int astep = 4 * 64 * 8;                  // shorts per ks
  const int bstep = 4 * PLANE * 8;

  float4v acc[4][2];
#pragma unroll
  for (int mt = 0; mt < 4; ++mt)
#pragma unroll
    for (int nt = 0; nt < 2; ++nt) acc[mt][nt] = (float4v){0.f, 0.f, 0.f, 0.f};

  short8v A0[4], B0[2], A1[4], B1[2], A2[4], B2[2];

#define SBAR __builtin_amdgcn_sched_barrier(0)
#define LOADSET(Ax, Bx)                                                        \
  {                                                                            \
    _Pragma("unroll") for (int nt = 0; nt < 2; ++nt)                           \
        Bx[nt] = *(const short8v*)(bp + nt * 128);                             \
    _Pragma("unroll") for (int mt = 0; mt < 4; ++mt)                           \
        Ax[mt] = *(const short8v*)(ap + mt * 128);                             \
    ap += astep; bp += bstep;                                                  \
  }
#define MFMASET(Ax, Bx)                                                        \
  {                                                                            \
    __builtin_amdgcn_s_setprio(1);                                             \
    _Pragma("unroll") for (int mt = 0; mt < 4; ++mt)                           \
        _Pragma("unroll") for (int nt = 0; nt < 2; ++nt)                       \
            acc[mt][nt] = __builtin_amdgcn_mfma_f32_16x16x32_bf16(             \
                Ax[mt], Bx[nt], acc[mt][nt], 0, 0, 0);                         \
    __builtin_amdgcn_s_setprio(0);                                             \
  }

  // depth-3 rotation, order PINNED: loads for trip k+2 issue before MFMA of
  // trip k; 2 loadsets (12 loads) always in flight ahead of each MFMASET.
  LOADSET(A0, B0);                               // trip 0
  LOADSET(A1, B1);                               // trip 1
  SBAR;
  for (int k = 0; k < T - 3; k += 3) {
    LOADSET(A2, B2); SBAR;                       // trip k+2
    MFMASET(A0, B0); SBAR;                       // trip k
    LOADSET(A0, B0); SBAR;                       // trip k+3
    MFMASET(A1, B1); SBAR;                       // trip k+1
    LOADSET(A1, B1); SBAR;                       // trip k+4
    MFMASET(A2, B2); SBAR;                       // trip k+2
  }
  LOADSET(A2, B2); SBAR;                         // trip T-1
  MFMASET(A0, B0);                               // trip T-3
  MFMASET(A1, B1);                               // trip T-2
  MFMASET(A2, B2);                               // trip T-1
#undef LOADSET
#undef MFMASET
#undef SBAR

  // C/D: col(n) = lane&15, row(m) = quad*4 + reg
  const int vb = d * PLANE + n0 + m15;
#pragma unroll
  for (int mt = 0; mt < 4; ++mt) {
#pragma unroll
    for (int r = 0; r < 4; ++r) {
      int m = mt * 16 + quad * 4 + r;
      float bv = bias[m];
      float* op = outb + (size_t)m * V3 + vb;
#pragma unroll
      for (int nt = 0; nt < 2; ++nt)
        op[nt * 16] = acc[mt][nt][r] + bv;
    }
  }
}

extern "C" void kernel_launch(void* const* d_in, const int* in_sizes, int n_in,
                              void* d_out, int out_size, void* d_ws, size_t ws_size,
                              hipStream_t stream) {
  const float* x    = (const float*)d_in[0];   // [2,32,1,48,48,48]
  const float* w    = (const float*)d_in[1];   // [64,32,1,1,1,10]
  const float* bias = (const float*)d_in[2];   // [64]
  float* out = (float*)d_out;                  // [2,64,1,48,48,48]

  ushort_t* Afr = (ushort_t*)d_ws;                         // 122880 B
  ushort_t* Bq  = (ushort_t*)((char*)d_ws + 131072);
  const size_t SB = (size_t)1152 * PLANE * 8 * 2;          // 42.5 MB per batch
  const bool both = (ws_size >= 131072 + 2 * SB);

  prep_kernel<<<240, 256, 0, stream>>>(w, Afr);
  if (both) {
    bq_kernel<<<dim3(48, 16, 2), 256, 0, stream>>>(x, Bq);
    gemm_kernel<<<dim3(864, 1, 2), 256, 0, stream>>>(Bq, Afr, bias, out);
  } else {
    for (int b = 0; b < 2; ++b) {
      bq_kernel<<<dim3(48, 16, 1), 256, 0, stream>>>(x + (size_t)b * 32 * V3, Bq);
      gemm_kernel<<<dim3(864, 1, 1), 256, 0, stream>>>(Bq, Afr, bias,
                                                       out + (size_t)b * NO * V3);
    }
  }
}